// Round 4
// baseline (741.098 us; speedup 1.0000x reference)
//
#include <hip/hip_runtime.h>
#include <stdint.h>

#define DEV __device__ __forceinline__

typedef __attribute__((ext_vector_type(8))) __bf16 bf16x8;
typedef __attribute__((ext_vector_type(4))) float f32x4;

DEV unsigned short f2bf(float f){
  union { float fv; unsigned u; } v; v.fv = f;
  unsigned r = v.u + 0x7fffu + ((v.u >> 16) & 1u);
  return (unsigned short)(r >> 16);
}

// async global->LDS, 16B per lane. LDS dest = wave-uniform base + lane*16.
DEV void gload16(const void* g, void* l){
  __builtin_amdgcn_global_load_lds((const __attribute__((address_space(1))) void*)g,
                                   (__attribute__((address_space(3))) void*)l,
                                   16, 0, 0);
}

// ---------------- fp32 -> bf16 convert ----------------
__global__ void k_cvt(const float* __restrict__ src, unsigned short* __restrict__ dst){
  const int i = (blockIdx.x * blockDim.x + threadIdx.x) << 2;
  const float4 v = *(const float4*)(src + i);
  ushort4 o;
  o.x = f2bf(v.x); o.y = f2bf(v.y); o.z = f2bf(v.z); o.w = f2bf(v.w);
  *(ushort4*)(dst + i) = o;
}

// ---------------- GEMM: C[M,N] = A[M,K] * B[N,K]^T, K=1024, 128x128 tile, BK=64 ----------------
template<int MODE>
__launch_bounds__(256)
__global__ void k_gemm(const unsigned short* __restrict__ A,
                       const unsigned short* __restrict__ Bm,
                       const float* __restrict__ bias,
                       float* __restrict__ outF,
                       unsigned short* __restrict__ Qm,
                       unsigned short* __restrict__ Km,
                       unsigned short* __restrict__ VTm)
{
  __shared__ unsigned short As[128*64];
  __shared__ unsigned short Bs[128*64];
  const int tid  = threadIdx.x;
  const int lane = tid & 63;
  const int wid  = tid >> 6;
  const int wr   = wid >> 1;
  const int wc   = wid & 1;
  const int r0   = blockIdx.y * 128;
  const int c0   = blockIdx.x * 128;
  const int l15  = lane & 15;
  const int l4   = lane >> 4;

  f32x4 acc[4][4];
#pragma unroll
  for (int m = 0; m < 4; ++m)
#pragma unroll
    for (int n = 0; n < 4; ++n)
      acc[m][n] = (f32x4){0.f, 0.f, 0.f, 0.f};

  for (int k0 = 0; k0 < 1024; k0 += 64){
#pragma unroll
    for (int i = 0; i < 4; ++i){
      const int sb   = (i*4 + wid)*64;
      const int slot = sb + lane;
      const int row  = slot >> 3;
      const int cg   = (slot & 7) ^ (row & 7);     // source-side swizzle
      gload16(A  + (size_t)(r0 + row)*1024 + k0 + cg*8, (void*)(As + sb*8));
      gload16(Bm + (size_t)(c0 + row)*1024 + k0 + cg*8, (void*)(Bs + sb*8));
    }
    __syncthreads();
#pragma unroll
    for (int kk = 0; kk < 2; ++kk){
      bf16x8 af[4], bf[4];
#pragma unroll
      for (int m = 0; m < 4; ++m){
        const int row = wr*64 + m*16 + l15;
        const int ch  = (kk*4 + l4) ^ (row & 7);
        af[m] = *(const bf16x8*)(As + row*64 + ch*8);
      }
#pragma unroll
      for (int n = 0; n < 4; ++n){
        const int row = wc*64 + n*16 + l15;
        const int ch  = (kk*4 + l4) ^ (row & 7);
        bf[n] = *(const bf16x8*)(Bs + row*64 + ch*8);
      }
#pragma unroll
      for (int m = 0; m < 4; ++m)
#pragma unroll
        for (int n = 0; n < 4; ++n)
          acc[m][n] = __builtin_amdgcn_mfma_f32_16x16x32_bf16(af[m], bf[n], acc[m][n], 0, 0, 0);
    }
    __syncthreads();
  }

  if (MODE == 0){
#pragma unroll
    for (int n = 0; n < 4; ++n){
      const int f     = c0 + wc*64 + n*16 + l15;
      const float bs  = bias[f];
      const int which = f >> 10;
      const int fi    = f & 1023;
      const int h     = fi >> 6;
      const int d     = fi & 63;
#pragma unroll
      for (int m = 0; m < 4; ++m){
        const int rb = r0 + wr*64 + m*16 + (l4 << 2);
#pragma unroll
        for (int j = 0; j < 4; ++j){
          const int r = rb + j;
          const int t = r >> 2;
          const int b = r & 3;
          float v = acc[m][n][j] + bs;
          if (which == 0) v *= 0.125f;                 // q scaling Dh^-0.5
          const unsigned short bv = f2bf(v);
          const int bh = b*16 + h;
          if (which == 0)      Qm [((size_t)bh*2048 + t)*64 + d] = bv;
          else if (which == 1) Km [((size_t)bh*2048 + t)*64 + d] = bv;
          else                 VTm[((size_t)bh*64 + d)*2048 + t] = bv;
        }
      }
    }
  } else {
#pragma unroll
    for (int m = 0; m < 4; ++m){
      const int rb = r0 + wr*64 + m*16 + (l4 << 2);
#pragma unroll
      for (int n = 0; n < 4; ++n){
        const int f    = c0 + wc*64 + n*16 + l15;
        const float bs = bias[f];
#pragma unroll
        for (int j = 0; j < 4; ++j)
          outF[(size_t)(rb + j)*1024 + f] = acc[m][n][j] + bs;
      }
    }
  }
}

// ---------------- PV: direct-global K/V/Q, swapped QK^T, barrier-free main loop ----------------
// ctx[t,b,h*64+d] = (1/l) sum_s exp(s) * V ;  linv[bh,t] = 1/l
__launch_bounds__(512)
__global__ void k_pv(const unsigned short* __restrict__ Qm,
                     const unsigned short* __restrict__ Km,
                     const unsigned short* __restrict__ VTm,
                     float* __restrict__ linv,
                     unsigned short* __restrict__ ctx)
{
  __shared__ unsigned short Ws[128*64];   // P tile bf16; rows are wave-private
  const int tid = threadIdx.x, lane = tid & 63, wid = tid >> 6;
  const int l15 = lane & 15, l4 = lane >> 4;
  const int bh = blockIdx.y;
  const int t0 = blockIdx.x * 128;
  const unsigned short* Qb = Qm  + (size_t)bh*131072;
  const unsigned short* Kb = Km  + (size_t)bh*131072;
  const unsigned short* Vb = VTm + (size_t)bh*131072;

  // Q fragments straight from global (q-rows = wid*16 + l15)
  bf16x8 aq[2];
#pragma unroll
  for (int kk = 0; kk < 2; ++kk)
    aq[kk] = *(const bf16x8*)(Qb + (size_t)(t0 + wid*16 + l15)*64 + (kk*4 + l4)*8);

  f32x4 oacc[4];
#pragma unroll
  for (int n = 0; n < 4; ++n) oacc[n] = (f32x4){0.f,0.f,0.f,0.f};
  float lacc = 0.f;

  const int wrow = wid*16 + l15;          // this lane's q-row in Ws
  const int rx7  = l15 & 7;               // (wrow & 7) since wid*16 % 8 == 0

  for (int s0 = 0; s0 < 2048; s0 += 64){
    // --- QK^T swapped: sacc[n] holds S^T rows s = s0+n*16+l4*4+j, col q = l15 ---
#pragma unroll
    for (int n = 0; n < 4; ++n){
      f32x4 sacc = (f32x4){0.f,0.f,0.f,0.f};
#pragma unroll
      for (int kk = 0; kk < 2; ++kk){
        const bf16x8 ak = *(const bf16x8*)(Kb + (size_t)(s0 + n*16 + l15)*64 + (kk*4 + l4)*8);
        sacc = __builtin_amdgcn_mfma_f32_16x16x32_bf16(ak, aq[kk], sacc, 0, 0, 0);
      }
      // exp + pack 4 consecutive s into one 8B LDS write (wave-private row)
      float p0 = __expf(sacc[0]), p1 = __expf(sacc[1]);
      float p2 = __expf(sacc[2]), p3 = __expf(sacc[3]);
      lacc += (p0 + p1) + (p2 + p3);
      ushort4 pk;
      pk.x = f2bf(p0); pk.y = f2bf(p1); pk.z = f2bf(p2); pk.w = f2bf(p3);
      const int g = (n*4 + l4) ^ (rx7 << 1);       // 8B-granule swizzle
      *(ushort4*)(Ws + wrow*64 + g*4) = pk;
    }
    // --- read P rows back as PV A-operand (same wave-private rows) ---
    bf16x8 aw[2];
#pragma unroll
    for (int kk = 0; kk < 2; ++kk){
      const int c = (kk*4 + l4) ^ rx7;             // equivalent 16B-chunk swizzle
      aw[kk] = *(const bf16x8*)(Ws + wrow*64 + c*8);
    }
    // --- PV: O[q][d] += P * V  (B-operand = V^T d-rows from global) ---
#pragma unroll
    for (int n = 0; n < 4; ++n){
#pragma unroll
      for (int kk = 0; kk < 2; ++kk){
        const bf16x8 bv = *(const bf16x8*)(Vb + (size_t)(n*16 + l15)*2048 + s0 + (kk*4 + l4)*8);
        oacc[n] = __builtin_amdgcn_mfma_f32_16x16x32_bf16(aw[kk], bv, oacc[n], 0, 0, 0);
      }
    }
  }

  // row-sum: lane holds partial for q-row l15; combine the 4 l4 copies
  lacc += __shfl_xor(lacc, 16);
  lacc += __shfl_xor(lacc, 32);
  const float rl = 1.0f / lacc;
  if (lane < 16)
    linv[(size_t)bh*2048 + t0 + wid*16 + lane] = rl;

  // redistribute: output rows are q = l4*4+j
  float rlj[4];
#pragma unroll
  for (int j = 0; j < 4; ++j)
    rlj[j] = __shfl(rl, (l4 << 2) + j);

  const int b = bh >> 4, h = bh & 15;
#pragma unroll
  for (int n = 0; n < 4; ++n){
#pragma unroll
    for (int j = 0; j < 4; ++j){
      const int t = t0 + wid*16 + (l4 << 2) + j;
      const int d = n*16 + l15;
      ctx[((size_t)t*4 + b)*1024 + h*64 + d] = f2bf(oacc[n][j] * rlj[j]);
    }
  }
}

// ---------------- avg weights: zero LDS, zero barriers, direct-global fragments ----------------
__launch_bounds__(256)
__global__ void k_avg(const unsigned short* __restrict__ Qm,
                      const unsigned short* __restrict__ Km,
                      const float* __restrict__ linv,
                      float* __restrict__ avg)
{
  const int tid = threadIdx.x, lane = tid & 63, wid = tid >> 6;
  const int l15 = lane & 15, l4 = lane >> 4;
  const int b   = blockIdx.z;
  const int t0  = blockIdx.y * 128;
  const int s0  = blockIdx.x * 128;

  float wacc[2][8][4];
#pragma unroll
  for (int m = 0; m < 2; ++m)
#pragma unroll
    for (int n = 0; n < 8; ++n)
#pragma unroll
      for (int j = 0; j < 4; ++j) wacc[m][n][j] = 0.f;

  for (int h = 0; h < 16; ++h){
    const int bh = b*16 + h;
    const unsigned short* Qb = Qm + (size_t)bh*131072;
    const unsigned short* Kb = Km + (size_t)bh*131072;

    float4 lj[2];
#pragma unroll
    for (int m = 0; m < 2; ++m){
      lj[m] = *(const float4*)(linv + (size_t)bh*2048 + t0 + wid*32 + m*16 + (l4 << 2));
      lj[m].x *= 0.0625f; lj[m].y *= 0.0625f; lj[m].z *= 0.0625f; lj[m].w *= 0.0625f;
    }

    bf16x8 aq[2][2];
#pragma unroll
    for (int m = 0; m < 2; ++m)
#pragma unroll
      for (int kk = 0; kk < 2; ++kk)
        aq[m][kk] = *(const bf16x8*)(Qb + (size_t)(t0 + wid*32 + m*16 + l15)*64 + (kk*4 + l4)*8);

#pragma unroll
    for (int nh = 0; nh < 2; ++nh){
      bf16x8 bk[4][2];
#pragma unroll
      for (int n4 = 0; n4 < 4; ++n4)
#pragma unroll
        for (int kk = 0; kk < 2; ++kk)
          bk[n4][kk] = *(const bf16x8*)(Kb + (size_t)(s0 + (nh*4 + n4)*16 + l15)*64 + (kk*4 + l4)*8);
#pragma unroll
      for (int n4 = 0; n4 < 4; ++n4){
#pragma unroll
        for (int m = 0; m < 2; ++m){
          f32x4 sacc = (f32x4){0.f,0.f,0.f,0.f};
          sacc = __builtin_amdgcn_mfma_f32_16x16x32_bf16(aq[m][0], bk[n4][0], sacc, 0, 0, 0);
          sacc = __builtin_amdgcn_mfma_f32_16x16x32_bf16(aq[m][1], bk[n4][1], sacc, 0, 0, 0);
          const int n = nh*4 + n4;
          wacc[m][n][0] += __expf(sacc[0]) * lj[m].x;
          wacc[m][n][1] += __expf(sacc[1]) * lj[m].y;
          wacc[m][n][2] += __expf(sacc[2]) * lj[m].z;
          wacc[m][n][3] += __expf(sacc[3]) * lj[m].w;
        }
      }
    }
  }

#pragma unroll
  for (int m = 0; m < 2; ++m)
#pragma unroll
    for (int n = 0; n < 8; ++n)
#pragma unroll
      for (int j = 0; j < 4; ++j){
        const int t = t0 + wid*32 + m*16 + (l4 << 2) + j;
        const int s = s0 + n*16 + l15;
        avg[((size_t)b*2048 + t)*2048 + s] = wacc[m][n][j];
      }
}

extern "C" void kernel_launch(void* const* d_in, const int* in_sizes, int n_in,
                              void* d_out, int out_size, void* d_ws, size_t ws_size,
                              hipStream_t stream)
{
  const float* x    = (const float*)d_in[0];
  const float* wqkv = (const float*)d_in[1];
  const float* bqkv = (const float*)d_in[2];
  const float* wout = (const float*)d_in[3];
  const float* bout = (const float*)d_in[4];
  float* out = (float*)d_out;

  char* ws = (char*)d_ws;
  unsigned short* xb    = (unsigned short*)(ws);
  unsigned short* wqkvb = (unsigned short*)(ws + ((size_t)16 << 20));
  unsigned short* woutb = (unsigned short*)(ws + ((size_t)24 << 20));
  unsigned short* Qm    = (unsigned short*)(ws + ((size_t)26 << 20));
  unsigned short* Km    = (unsigned short*)(ws + ((size_t)42 << 20));
  unsigned short* VTm   = (unsigned short*)(ws + ((size_t)58 << 20));
  unsigned short* ctx   = (unsigned short*)(ws + ((size_t)74 << 20));
  float* linv = (float*)(ws + ((size_t)90 << 20));

  k_cvt<<<8192, 256, 0, stream>>>(x,    xb);
  k_cvt<<<3072, 256, 0, stream>>>(wqkv, wqkvb);
  k_cvt<<<1024, 256, 0, stream>>>(wout, woutb);

  k_gemm<0><<<dim3(24, 64), 256, 0, stream>>>(xb, wqkvb, bqkv, nullptr, Qm, Km, VTm);
  k_pv     <<<dim3(16, 64), 512, 0, stream>>>(Qm, Km, VTm, linv, ctx);
  k_avg    <<<dim3(16, 16, 4), 256, 0, stream>>>(Qm, Km, linv, out + 8388608);
  k_gemm<1><<<dim3(8, 64), 256, 0, stream>>>(ctx, woutb, bout, out, nullptr, nullptr, nullptr);
}

// Round 5
// 333.269 us; speedup vs baseline: 2.2237x; 2.2237x over previous
//
#include <hip/hip_runtime.h>
#include <stdint.h>

#define DEV __device__ __forceinline__

typedef __attribute__((ext_vector_type(8))) __bf16 bf16x8;
typedef __attribute__((ext_vector_type(4))) float f32x4;

DEV unsigned short f2bf(float f){
  union { float fv; unsigned u; } v; v.fv = f;
  unsigned r = v.u + 0x7fffu + ((v.u >> 16) & 1u);
  return (unsigned short)(r >> 16);
}

// async global->LDS, 16B per lane. LDS dest = wave-uniform base + lane*16.
DEV void gload16(const void* g, void* l){
  __builtin_amdgcn_global_load_lds((const __attribute__((address_space(1))) void*)g,
                                   (__attribute__((address_space(3))) void*)l,
                                   16, 0, 0);
}

// ---------------- fp32 -> bf16 convert ----------------
__global__ void k_cvt(const float* __restrict__ src, unsigned short* __restrict__ dst){
  const int i = (blockIdx.x * blockDim.x + threadIdx.x) << 2;
  const float4 v = *(const float4*)(src + i);
  ushort4 o;
  o.x = f2bf(v.x); o.y = f2bf(v.y); o.z = f2bf(v.z); o.w = f2bf(v.w);
  *(ushort4*)(dst + i) = o;
}

// ---------------- GEMM: C[M,N] = A[M,K] * B[N,K]^T, K=1024, 128x128 tile, BK=64 ----------------
template<int MODE>
__launch_bounds__(256)
__global__ void k_gemm(const unsigned short* __restrict__ A,
                       const unsigned short* __restrict__ Bm,
                       const float* __restrict__ bias,
                       float* __restrict__ outF,
                       unsigned short* __restrict__ Qm,
                       unsigned short* __restrict__ Km,
                       unsigned short* __restrict__ VTm)
{
  __shared__ unsigned short As[128*64];
  __shared__ unsigned short Bs[128*64];
  const int tid  = threadIdx.x;
  const int lane = tid & 63;
  const int wid  = tid >> 6;
  const int wr   = wid >> 1;
  const int wc   = wid & 1;
  const int r0   = blockIdx.y * 128;
  const int c0   = blockIdx.x * 128;
  const int l15  = lane & 15;
  const int l4   = lane >> 4;

  f32x4 acc[4][4];
#pragma unroll
  for (int m = 0; m < 4; ++m)
#pragma unroll
    for (int n = 0; n < 4; ++n)
      acc[m][n] = (f32x4){0.f, 0.f, 0.f, 0.f};

  for (int k0 = 0; k0 < 1024; k0 += 64){
#pragma unroll
    for (int i = 0; i < 4; ++i){
      const int sb   = (i*4 + wid)*64;
      const int slot = sb + lane;
      const int row  = slot >> 3;
      const int cg   = (slot & 7) ^ (row & 7);     // source-side swizzle
      gload16(A  + (size_t)(r0 + row)*1024 + k0 + cg*8, (void*)(As + sb*8));
      gload16(Bm + (size_t)(c0 + row)*1024 + k0 + cg*8, (void*)(Bs + sb*8));
    }
    __syncthreads();
#pragma unroll
    for (int kk = 0; kk < 2; ++kk){
      bf16x8 af[4], bf[4];
#pragma unroll
      for (int m = 0; m < 4; ++m){
        const int row = wr*64 + m*16 + l15;
        const int ch  = (kk*4 + l4) ^ (row & 7);
        af[m] = *(const bf16x8*)(As + row*64 + ch*8);
      }
#pragma unroll
      for (int n = 0; n < 4; ++n){
        const int row = wc*64 + n*16 + l15;
        const int ch  = (kk*4 + l4) ^ (row & 7);
        bf[n] = *(const bf16x8*)(Bs + row*64 + ch*8);
      }
#pragma unroll
      for (int m = 0; m < 4; ++m)
#pragma unroll
        for (int n = 0; n < 4; ++n)
          acc[m][n] = __builtin_amdgcn_mfma_f32_16x16x32_bf16(af[m], bf[n], acc[m][n], 0, 0, 0);
    }
    __syncthreads();
  }

  if (MODE == 0){
#pragma unroll
    for (int n = 0; n < 4; ++n){
      const int f     = c0 + wc*64 + n*16 + l15;
      const float bs  = bias[f];
      const int which = f >> 10;
      const int fi    = f & 1023;
      const int h     = fi >> 6;
      const int d     = fi & 63;
#pragma unroll
      for (int m = 0; m < 4; ++m){
        const int rb = r0 + wr*64 + m*16 + (l4 << 2);
#pragma unroll
        for (int j = 0; j < 4; ++j){
          const int r = rb + j;
          const int t = r >> 2;
          const int b = r & 3;
          float v = acc[m][n][j] + bs;
          if (which == 0) v *= 0.125f;                 // q scaling Dh^-0.5
          const unsigned short bv = f2bf(v);
          const int bh = b*16 + h;
          if (which == 0)      Qm [((size_t)bh*2048 + t)*64 + d] = bv;
          else if (which == 1) Km [((size_t)bh*2048 + t)*64 + d] = bv;
          else                 VTm[((size_t)bh*64 + d)*2048 + t] = bv;
        }
      }
    }
  } else {
#pragma unroll
    for (int m = 0; m < 4; ++m){
      const int rb = r0 + wr*64 + m*16 + (l4 << 2);
#pragma unroll
      for (int n = 0; n < 4; ++n){
        const int f    = c0 + wc*64 + n*16 + l15;
        const float bs = bias[f];
#pragma unroll
        for (int j = 0; j < 4; ++j)
          outF[(size_t)(rb + j)*1024 + f] = acc[m][n][j] + bs;
      }
    }
  }
}

// ---------------- PV fused with softmax denominator ----------------
// K/V staged in LDS (shared by 8 waves, dbuf); Q direct from global (no sharing).
// Ws rows are wave-private -> 1 barrier per s-tile.
__launch_bounds__(512)
__global__ void k_pv(const unsigned short* __restrict__ Qm,
                     const unsigned short* __restrict__ Km,
                     const unsigned short* __restrict__ VTm,
                     float* __restrict__ linv,
                     unsigned short* __restrict__ ctx)
{
  __shared__ unsigned short Ws[128*64];     // 16KB (wave-private rows)
  __shared__ unsigned short Ks[2][64*64];   // 16KB dbuf
  __shared__ unsigned short Vs[2][64*64];   // 16KB dbuf  (V^T tile: [d][s])
  const int tid = threadIdx.x, lane = tid & 63, wid = tid >> 6;
  const int l15 = lane & 15, l4 = lane >> 4;
  const int bh = blockIdx.y;
  const int t0 = blockIdx.x * 128;
  const unsigned short* Qb = Qm  + (size_t)bh*131072;
  const unsigned short* Kb = Km  + (size_t)bh*131072;
  const unsigned short* Vb = VTm + (size_t)bh*131072;

  // stage K/V tile 0
  {
    const int slot = tid;
    const int row = slot >> 3;
    const int cg = (slot & 7) ^ (row & 7);
    gload16(Kb + (size_t)row*64 + cg*8, (void*)(Ks[0] + slot*8));
    gload16(Vb + (size_t)row*2048 + cg*8, (void*)(Vs[0] + slot*8));
  }
  // Q fragments direct from global (q-rows = wid*16 + l15; used by this wave only)
  bf16x8 aq[2];
#pragma unroll
  for (int kk = 0; kk < 2; ++kk)
    aq[kk] = *(const bf16x8*)(Qb + (size_t)(t0 + wid*16 + l15)*64 + (kk*4 + l4)*8);
  __syncthreads();

  f32x4 oacc[4];
#pragma unroll
  for (int n = 0; n < 4; ++n) oacc[n] = (f32x4){0.f,0.f,0.f,0.f};
  float lacc[4];
#pragma unroll
  for (int j = 0; j < 4; ++j) lacc[j] = 0.f;

  for (int s0 = 0; s0 < 2048; s0 += 64){
    const int cur = (s0 >> 6) & 1;
    if (s0 + 64 < 2048){
      const int slot = tid;
      const int row = slot >> 3;
      const int cg = (slot & 7) ^ (row & 7);
      gload16(Kb + (size_t)(s0 + 64 + row)*64 + cg*8, (void*)(Ks[cur^1] + slot*8));
      gload16(Vb + (size_t)row*2048 + (s0 + 64) + cg*8, (void*)(Vs[cur^1] + slot*8));
    }
    // QK^T + exp -> Ws (wave-private rows; no barrier before aw read)
#pragma unroll
    for (int n = 0; n < 4; ++n){
      f32x4 sacc = (f32x4){0.f,0.f,0.f,0.f};
#pragma unroll
      for (int kk = 0; kk < 2; ++kk){
        const int sr = n*16 + l15;
        const int ch = (kk*4 + l4) ^ (sr & 7);
        const bf16x8 bk = *(const bf16x8*)(Ks[cur] + sr*64 + ch*8);
        sacc = __builtin_amdgcn_mfma_f32_16x16x32_bf16(aq[kk], bk, sacc, 0, 0, 0);
      }
#pragma unroll
      for (int j = 0; j < 4; ++j){
        const float p = __expf(sacc[j]);             // scores bounded; no max subtraction
        lacc[j] += p;
        const int row = wid*16 + (l4 << 2) + j;
        const int scol = n*16 + l15;
        const int ch = (scol >> 3) ^ (row & 7);
        Ws[row*64 + ch*8 + (scol & 7)] = f2bf(p);
      }
    }
    bf16x8 aw[2];
#pragma unroll
    for (int kk = 0; kk < 2; ++kk){
      const int qr = wid*16 + l15;
      const int ch = (kk*4 + l4) ^ (qr & 7);
      aw[kk] = *(const bf16x8*)(Ws + qr*64 + ch*8);
    }
#pragma unroll
    for (int n = 0; n < 4; ++n){
#pragma unroll
      for (int kk = 0; kk < 2; ++kk){
        const int dr = n*16 + l15;
        const int ch = (kk*4 + l4) ^ (dr & 7);
        const bf16x8 bv = *(const bf16x8*)(Vs[cur] + dr*64 + ch*8);
        oacc[n] = __builtin_amdgcn_mfma_f32_16x16x32_bf16(aw[kk], bv, oacc[n], 0, 0, 0);
      }
    }
    __syncthreads();   // drains stage loads; protects buffer reuse + Ws overwrite
  }

  float rl[4];
#pragma unroll
  for (int j = 0; j < 4; ++j){
#pragma unroll
    for (int o = 1; o < 16; o <<= 1) lacc[j] += __shfl_xor(lacc[j], o);
    rl[j] = 1.0f / lacc[j];
  }
  if (l15 == 0){
#pragma unroll
    for (int j = 0; j < 4; ++j){
      const int t = t0 + wid*16 + (l4 << 2) + j;
      linv[(size_t)bh*2048 + t] = rl[j];
    }
  }

  const int b = bh >> 4, h = bh & 15;
#pragma unroll
  for (int n = 0; n < 4; ++n){
#pragma unroll
    for (int j = 0; j < 4; ++j){
      const int t = t0 + wid*16 + (l4 << 2) + j;
      const int d = n*16 + l15;
      ctx[((size_t)t*4 + b)*1024 + h*64 + d] = f2bf(oacc[n][j] * rl[j]);
    }
  }
}

// ---------------- avg weights ----------------
// t-tile 64, s-tile 128. K staged in LDS (shared by 4 waves, dbuf 32KB);
// Q and linv direct from global (no cross-wave sharing). 1 barrier per head.
__launch_bounds__(256)
__global__ void k_avg(const unsigned short* __restrict__ Qm,
                      const unsigned short* __restrict__ Km,
                      const float* __restrict__ linv,
                      float* __restrict__ avg)
{
  __shared__ unsigned short Ks[2][128*64];   // 32KB
  const int tid = threadIdx.x, lane = tid & 63, wid = tid >> 6;
  const int l15 = lane & 15, l4 = lane >> 4;
  const int b   = blockIdx.z;
  const int t0  = blockIdx.y * 64;
  const int s0  = blockIdx.x * 128;

  float wacc[8][4];
#pragma unroll
  for (int n = 0; n < 8; ++n)
#pragma unroll
    for (int j = 0; j < 4; ++j) wacc[n][j] = 0.f;

  // prologue: stage head 0 K tile
  {
    const unsigned short* Kb = Km + (size_t)(b*16)*131072;
#pragma unroll
    for (int i = 0; i < 4; ++i){
      const int slot = i*256 + tid;
      const int row = slot >> 3;
      const int cg = (slot & 7) ^ (row & 7);
      gload16(Kb + (size_t)(s0 + row)*64 + cg*8, (void*)(Ks[0] + slot*8));
    }
  }
  __syncthreads();

  for (int h = 0; h < 16; ++h){
    const int cur = h & 1;
    if (h < 15){
      const unsigned short* Kb = Km + (size_t)(b*16 + h + 1)*131072;
#pragma unroll
      for (int i = 0; i < 4; ++i){
        const int slot = i*256 + tid;
        const int row = slot >> 3;
        const int cg = (slot & 7) ^ (row & 7);
        gload16(Kb + (size_t)(s0 + row)*64 + cg*8, (void*)(Ks[cur^1] + slot*8));
      }
    }
    const int bh = b*16 + h;
    const unsigned short* Qb = Qm + (size_t)bh*131072;

    bf16x8 aq[2];
#pragma unroll
    for (int kk = 0; kk < 2; ++kk)
      aq[kk] = *(const bf16x8*)(Qb + (size_t)(t0 + wid*16 + l15)*64 + (kk*4 + l4)*8);

    float4 lj = *(const float4*)(linv + (size_t)bh*2048 + t0 + wid*16 + (l4 << 2));
    lj.x *= 0.0625f; lj.y *= 0.0625f; lj.z *= 0.0625f; lj.w *= 0.0625f;

#pragma unroll
    for (int n = 0; n < 8; ++n){
      f32x4 sacc = (f32x4){0.f,0.f,0.f,0.f};
#pragma unroll
      for (int kk = 0; kk < 2; ++kk){
        const int row = n*16 + l15;
        const int ch  = (kk*4 + l4) ^ (row & 7);
        const bf16x8 bk = *(const bf16x8*)(Ks[cur] + row*64 + ch*8);
        sacc = __builtin_amdgcn_mfma_f32_16x16x32_bf16(aq[kk], bk, sacc, 0, 0, 0);
      }
      wacc[n][0] += __expf(sacc[0]) * lj.x;
      wacc[n][1] += __expf(sacc[1]) * lj.y;
      wacc[n][2] += __expf(sacc[2]) * lj.z;
      wacc[n][3] += __expf(sacc[3]) * lj.w;
    }
    __syncthreads();
  }

#pragma unroll
  for (int n = 0; n < 8; ++n)
#pragma unroll
    for (int j = 0; j < 4; ++j){
      const int t = t0 + wid*16 + (l4 << 2) + j;
      const int s = s0 + n*16 + l15;
      avg[((size_t)b*2048 + t)*2048 + s] = wacc[n][j];
    }
}

extern "C" void kernel_launch(void* const* d_in, const int* in_sizes, int n_in,
                              void* d_out, int out_size, void* d_ws, size_t ws_size,
                              hipStream_t stream)
{
  const float* x    = (const float*)d_in[0];
  const float* wqkv = (const float*)d_in[1];
  const float* bqkv = (const float*)d_in[2];
  const float* wout = (const float*)d_in[3];
  const float* bout = (const float*)d_in[4];
  float* out = (float*)d_out;

  char* ws = (char*)d_ws;
  unsigned short* xb    = (unsigned short*)(ws);
  unsigned short* wqkvb = (unsigned short*)(ws + ((size_t)16 << 20));
  unsigned short* woutb = (unsigned short*)(ws + ((size_t)24 << 20));
  unsigned short* Qm    = (unsigned short*)(ws + ((size_t)26 << 20));
  unsigned short* Km    = (unsigned short*)(ws + ((size_t)42 << 20));
  unsigned short* VTm   = (unsigned short*)(ws + ((size_t)58 << 20));
  unsigned short* ctx   = (unsigned short*)(ws + ((size_t)74 << 20));
  float* linv = (float*)(ws + ((size_t)90 << 20));

  k_cvt<<<8192, 256, 0, stream>>>(x,    xb);
  k_cvt<<<3072, 256, 0, stream>>>(wqkv, wqkvb);
  k_cvt<<<1024, 256, 0, stream>>>(wout, woutb);

  k_gemm<0><<<dim3(24, 64), 256, 0, stream>>>(xb, wqkvb, bqkv, nullptr, Qm, Km, VTm);
  k_pv     <<<dim3(16, 64), 512, 0, stream>>>(Qm, Km, VTm, linv, ctx);
  k_avg    <<<dim3(16, 32, 4), 256, 0, stream>>>(Qm, Km, linv, out + 8388608);
  k_gemm<1><<<dim3(8, 64), 256, 0, stream>>>(ctx, woutb, bout, out, nullptr, nullptr, nullptr);
}

// Round 6
// 299.405 us; speedup vs baseline: 2.4752x; 1.1131x over previous
//
#include <hip/hip_runtime.h>
#include <stdint.h>

#define DEV __device__ __forceinline__

typedef __attribute__((ext_vector_type(8))) __bf16 bf16x8;
typedef __attribute__((ext_vector_type(4))) __bf16 bf16x4;
typedef __attribute__((ext_vector_type(4))) float f32x4;

DEV unsigned short f2bf(float f){
  union { float fv; unsigned u; } v; v.fv = f;
  unsigned r = v.u + 0x7fffu + ((v.u >> 16) & 1u);
  return (unsigned short)(r >> 16);
}

// async global->LDS, 16B per lane. LDS dest = wave-uniform base + lane*16.
DEV void gload16(const void* g, void* l){
  __builtin_amdgcn_global_load_lds((const __attribute__((address_space(1))) void*)g,
                                   (__attribute__((address_space(3))) void*)l,
                                   16, 0, 0);
}

// ---------------- fp32 -> bf16 convert ----------------
__global__ void k_cvt(const float* __restrict__ src, unsigned short* __restrict__ dst){
  const int i = (blockIdx.x * blockDim.x + threadIdx.x) << 2;
  const float4 v = *(const float4*)(src + i);
  ushort4 o;
  o.x = f2bf(v.x); o.y = f2bf(v.y); o.z = f2bf(v.z); o.w = f2bf(v.w);
  *(ushort4*)(dst + i) = o;
}

// ---------------- GEMM: C[M,N] = A[M,K] * B[N,K]^T, K=1024, 128x128 tile, BK=64 ----------------
// MODE 0: qkv epilogue (bias, q-scale*log2e, scatter to Q/K/VT bf16), 24x64 grid XCD-swizzled
// MODE 1: out-proj epilogue (bias, fp32 store), 8x64 grid XCD-swizzled
template<int MODE>
__launch_bounds__(256)
__global__ void k_gemm(const unsigned short* __restrict__ A,
                       const unsigned short* __restrict__ Bm,
                       const float* __restrict__ bias,
                       float* __restrict__ outF,
                       unsigned short* __restrict__ Qm,
                       unsigned short* __restrict__ Km,
                       unsigned short* __restrict__ VTm)
{
  __shared__ unsigned short As[128*64];
  __shared__ unsigned short Bs[128*64];
  const int tid  = threadIdx.x;
  const int lane = tid & 63;
  const int wid  = tid >> 6;
  const int wr   = wid >> 1;
  const int wc   = wid & 1;
  // XCD-aware swizzle: keep one B-col-panel's row-blocks on one XCD
  const int wg = blockIdx.x;
  int bx, by;
  if (MODE == 0){ const int slot = wg >> 3; bx = (wg & 7) + 8*(slot >> 6); by = slot & 63; }
  else          { bx = wg & 7; by = wg >> 3; }
  const int r0   = by * 128;
  const int c0   = bx * 128;
  const int l15  = lane & 15;
  const int l4   = lane >> 4;

  f32x4 acc[4][4];
#pragma unroll
  for (int m = 0; m < 4; ++m)
#pragma unroll
    for (int n = 0; n < 4; ++n)
      acc[m][n] = (f32x4){0.f, 0.f, 0.f, 0.f};

  for (int k0 = 0; k0 < 1024; k0 += 64){
#pragma unroll
    for (int i = 0; i < 4; ++i){
      const int sb   = (i*4 + wid)*64;
      const int slot = sb + lane;
      const int row  = slot >> 3;
      const int cg   = (slot & 7) ^ (row & 7);     // source-side swizzle
      gload16(A  + (size_t)(r0 + row)*1024 + k0 + cg*8, (void*)(As + sb*8));
      gload16(Bm + (size_t)(c0 + row)*1024 + k0 + cg*8, (void*)(Bs + sb*8));
    }
    __syncthreads();
#pragma unroll
    for (int kk = 0; kk < 2; ++kk){
      bf16x8 af[4], bf[4];
#pragma unroll
      for (int m = 0; m < 4; ++m){
        const int row = wr*64 + m*16 + l15;
        const int ch  = (kk*4 + l4) ^ (row & 7);
        af[m] = *(const bf16x8*)(As + row*64 + ch*8);
      }
#pragma unroll
      for (int n = 0; n < 4; ++n){
        const int row = wc*64 + n*16 + l15;
        const int ch  = (kk*4 + l4) ^ (row & 7);
        bf[n] = *(const bf16x8*)(Bs + row*64 + ch*8);
      }
#pragma unroll
      for (int m = 0; m < 4; ++m)
#pragma unroll
        for (int n = 0; n < 4; ++n)
          acc[m][n] = __builtin_amdgcn_mfma_f32_16x16x32_bf16(af[m], bf[n], acc[m][n], 0, 0, 0);
    }
    __syncthreads();
  }

  if (MODE == 0){
#pragma unroll
    for (int n = 0; n < 4; ++n){
      const int f     = c0 + wc*64 + n*16 + l15;
      const float bs  = bias[f];
      const int which = f >> 10;
      const int fi    = f & 1023;
      const int h     = fi >> 6;
      const int d     = fi & 63;
#pragma unroll
      for (int m = 0; m < 4; ++m){
        const int rb = r0 + wr*64 + m*16 + (l4 << 2);
#pragma unroll
        for (int j = 0; j < 4; ++j){
          const int r = rb + j;
          const int t = r >> 2;
          const int b = r & 3;
          float v = acc[m][n][j] + bs;
          if (which == 0) v *= 0.18033688f;   // Dh^-0.5 * log2(e): scores become log2e*s
          const unsigned short bv = f2bf(v);
          const int bh = b*16 + h;
          if (which == 0)      Qm [((size_t)bh*2048 + t)*64 + d] = bv;
          else if (which == 1) Km [((size_t)bh*2048 + t)*64 + d] = bv;
          else                 VTm[((size_t)bh*64 + d)*2048 + t] = bv;
        }
      }
    }
  } else {
#pragma unroll
    for (int m = 0; m < 4; ++m){
      const int rb = r0 + wr*64 + m*16 + (l4 << 2);
#pragma unroll
      for (int n = 0; n < 4; ++n){
        const int f    = c0 + wc*64 + n*16 + l15;
        const float bs = bias[f];
#pragma unroll
        for (int j = 0; j < 4; ++j)
          outF[(size_t)(rb + j)*1024 + f] = acc[m][n][j] + bs;
      }
    }
  }
}

// ---------------- PV fused with softmax denominator ----------------
// Swapped QK^T (mfma(K,Q)) so each lane holds 4 consecutive s for one q-row:
// packed cvt_pk + ds_write_b64, scalar denominator. exp2 (Q pre-scaled by log2e).
// K/V staged in LDS (dbuf, shared by 8 waves); Q direct from global; Ws wave-private.
__launch_bounds__(512)
__global__ void k_pv(const unsigned short* __restrict__ Qm,
                     const unsigned short* __restrict__ Km,
                     const unsigned short* __restrict__ VTm,
                     float* __restrict__ linv,
                     unsigned short* __restrict__ ctx)
{
  __shared__ unsigned short Ws[128*64];     // 16KB (wave-private rows)
  __shared__ unsigned short Ks[2][64*64];   // 16KB dbuf
  __shared__ unsigned short Vs[2][64*64];   // 16KB dbuf  (V^T tile: [d][s])
  const int tid = threadIdx.x, lane = tid & 63, wid = tid >> 6;
  const int l15 = lane & 15, l4 = lane >> 4;
  // XCD swizzle: all 16 t-blocks of one bh land on one XCD (K/V L2-resident)
  const int wg = blockIdx.x;
  const int slotb = wg >> 3;
  const int bh = (wg & 7) + 8*(slotb >> 4);
  const int t0 = (slotb & 15) * 128;
  const unsigned short* Qb = Qm  + (size_t)bh*131072;
  const unsigned short* Kb = Km  + (size_t)bh*131072;
  const unsigned short* Vb = VTm + (size_t)bh*131072;

  // stage K/V tile 0
  {
    const int slot = tid;
    const int row = slot >> 3;
    const int cg = (slot & 7) ^ (row & 7);
    gload16(Kb + (size_t)row*64 + cg*8, (void*)(Ks[0] + slot*8));
    gload16(Vb + (size_t)row*2048 + cg*8, (void*)(Vs[0] + slot*8));
  }
  // Q fragments direct from global (q-rows = wid*16 + l15; used by this wave only)
  bf16x8 aq[2];
#pragma unroll
  for (int kk = 0; kk < 2; ++kk)
    aq[kk] = *(const bf16x8*)(Qb + (size_t)(t0 + wid*16 + l15)*64 + (kk*4 + l4)*8);
  __syncthreads();

  f32x4 oacc[4];
#pragma unroll
  for (int n = 0; n < 4; ++n) oacc[n] = (f32x4){0.f,0.f,0.f,0.f};
  float lacc = 0.f;

  const int wrow = wid*16 + l15;   // this lane's q-row in Ws
  const int rx   = l15 & 7;

  for (int s0 = 0; s0 < 2048; s0 += 64){
    const int cur = (s0 >> 6) & 1;
    if (s0 + 64 < 2048){
      const int slot = tid;
      const int row = slot >> 3;
      const int cg = (slot & 7) ^ (row & 7);
      gload16(Kb + (size_t)(s0 + 64 + row)*64 + cg*8, (void*)(Ks[cur^1] + slot*8));
      gload16(Vb + (size_t)row*2048 + (s0 + 64) + cg*8, (void*)(Vs[cur^1] + slot*8));
    }
    // swapped QK^T: sacc = S^T -> lane holds p[q=l15][s = n*16 + l4*4 + j]
#pragma unroll
    for (int n = 0; n < 4; ++n){
      f32x4 sacc = (f32x4){0.f,0.f,0.f,0.f};
#pragma unroll
      for (int kk = 0; kk < 2; ++kk){
        const int sr = n*16 + l15;
        const int ch = (kk*4 + l4) ^ (sr & 7);
        const bf16x8 ak = *(const bf16x8*)(Ks[cur] + sr*64 + ch*8);
        sacc = __builtin_amdgcn_mfma_f32_16x16x32_bf16(ak, aq[kk], sacc, 0, 0, 0);
      }
      f32x4 pv;
      pv[0] = __builtin_amdgcn_exp2f(sacc[0]);
      pv[1] = __builtin_amdgcn_exp2f(sacc[1]);
      pv[2] = __builtin_amdgcn_exp2f(sacc[2]);
      pv[3] = __builtin_amdgcn_exp2f(sacc[3]);
      lacc += (pv[0] + pv[1]) + (pv[2] + pv[3]);
      const bf16x4 pb = __builtin_convertvector(pv, bf16x4);
      const int g = (n*4 + l4) ^ (rx << 1);       // 8B-granule swizzle
      *(bf16x4*)(Ws + wrow*64 + g*4) = pb;
    }
    // read P rows back as PV A-operand (same wave-private rows)
    bf16x8 aw[2];
#pragma unroll
    for (int kk = 0; kk < 2; ++kk){
      const int c = (kk*4 + l4) ^ rx;             // matching 16B-chunk swizzle
      aw[kk] = *(const bf16x8*)(Ws + wrow*64 + c*8);
    }
#pragma unroll
    for (int n = 0; n < 4; ++n){
#pragma unroll
      for (int kk = 0; kk < 2; ++kk){
        const int dr = n*16 + l15;
        const int ch = (kk*4 + l4) ^ (dr & 7);
        const bf16x8 bv = *(const bf16x8*)(Vs[cur] + dr*64 + ch*8);
        oacc[n] = __builtin_amdgcn_mfma_f32_16x16x32_bf16(aw[kk], bv, oacc[n], 0, 0, 0);
      }
    }
    __syncthreads();   // drains stage loads; protects buffer reuse + Ws overwrite
  }

  // full row-sum for q = l15: combine the 4 l4 copies
  lacc += __shfl_xor(lacc, 16);
  lacc += __shfl_xor(lacc, 32);
  const float rl = 1.0f / lacc;
  if (lane < 16)
    linv[(size_t)bh*2048 + t0 + wid*16 + lane] = rl;

  // redistribute: output rows are q = l4*4 + j
  float rlj[4];
#pragma unroll
  for (int j = 0; j < 4; ++j)
    rlj[j] = __shfl(rl, (l4 << 2) + j);

  const int b = bh >> 4, h = bh & 15;
#pragma unroll
  for (int n = 0; n < 4; ++n){
#pragma unroll
    for (int j = 0; j < 4; ++j){
      const int t = t0 + wid*16 + (l4 << 2) + j;
      const int d = n*16 + l15;
      ctx[((size_t)t*4 + b)*1024 + h*64 + d] = f2bf(oacc[n][j] * rlj[j]);
    }
  }
}

// ---------------- avg weights ----------------
// t-tile 64, s-tile 128. K staged in LDS (dbuf 32KB, shared by 4 waves);
// Q/linv direct from global. exp2 (Q pre-scaled). XCD swizzle: (b,s0) pinned per XCD.
__launch_bounds__(256)
__global__ void k_avg(const unsigned short* __restrict__ Qm,
                      const unsigned short* __restrict__ Km,
                      const float* __restrict__ linv,
                      float* __restrict__ avg)
{
  __shared__ unsigned short Ks[2][128*64];   // 32KB
  const int tid = threadIdx.x, lane = tid & 63, wid = tid >> 6;
  const int l15 = lane & 15, l4 = lane >> 4;
  const int wg = blockIdx.x;                 // 2048
  const int slotb = wg >> 3;                 // 0..255
  const int combo = (wg & 7) + 8*(slotb >> 5);  // 0..63
  const int b   = combo >> 4;
  const int s0  = (combo & 15) * 128;
  const int t0  = (slotb & 31) * 64;

  float wacc[8][4];
#pragma unroll
  for (int n = 0; n < 8; ++n)
#pragma unroll
    for (int j = 0; j < 4; ++j) wacc[n][j] = 0.f;

  // prologue: stage head 0 K tile
  {
    const unsigned short* Kb = Km + (size_t)(b*16)*131072;
#pragma unroll
    for (int i = 0; i < 4; ++i){
      const int slot = i*256 + tid;
      const int row = slot >> 3;
      const int cg = (slot & 7) ^ (row & 7);
      gload16(Kb + (size_t)(s0 + row)*64 + cg*8, (void*)(Ks[0] + slot*8));
    }
  }
  __syncthreads();

  for (int h = 0; h < 16; ++h){
    const int cur = h & 1;
    if (h < 15){
      const unsigned short* Kb = Km + (size_t)(b*16 + h + 1)*131072;
#pragma unroll
      for (int i = 0; i < 4; ++i){
        const int slot = i*256 + tid;
        const int row = slot >> 3;
        const int cg = (slot & 7) ^ (row & 7);
        gload16(Kb + (size_t)(s0 + row)*64 + cg*8, (void*)(Ks[cur^1] + slot*8));
      }
    }
    const int bh = b*16 + h;
    const unsigned short* Qb = Qm + (size_t)bh*131072;

    bf16x8 aq[2];
#pragma unroll
    for (int kk = 0; kk < 2; ++kk)
      aq[kk] = *(const bf16x8*)(Qb + (size_t)(t0 + wid*16 + l15)*64 + (kk*4 + l4)*8);

    float4 lj = *(const float4*)(linv + (size_t)bh*2048 + t0 + wid*16 + (l4 << 2));
    lj.x *= 0.0625f; lj.y *= 0.0625f; lj.z *= 0.0625f; lj.w *= 0.0625f;

#pragma unroll
    for (int n = 0; n < 8; ++n){
      f32x4 sacc = (f32x4){0.f,0.f,0.f,0.f};
#pragma unroll
      for (int kk = 0; kk < 2; ++kk){
        const int row = n*16 + l15;
        const int ch  = (kk*4 + l4) ^ (row & 7);
        const bf16x8 bk = *(const bf16x8*)(Ks[cur] + row*64 + ch*8);
        sacc = __builtin_amdgcn_mfma_f32_16x16x32_bf16(aq[kk], bk, sacc, 0, 0, 0);
      }
      wacc[n][0] += __builtin_amdgcn_exp2f(sacc[0]) * lj.x;
      wacc[n][1] += __builtin_amdgcn_exp2f(sacc[1]) * lj.y;
      wacc[n][2] += __builtin_amdgcn_exp2f(sacc[2]) * lj.z;
      wacc[n][3] += __builtin_amdgcn_exp2f(sacc[3]) * lj.w;
    }
    __syncthreads();
  }

#pragma unroll
  for (int n = 0; n < 8; ++n)
#pragma unroll
    for (int j = 0; j < 4; ++j){
      const int t = t0 + wid*16 + (l4 << 2) + j;
      const int s = s0 + n*16 + l15;
      avg[((size_t)b*2048 + t)*2048 + s] = wacc[n][j];
    }
}

extern "C" void kernel_launch(void* const* d_in, const int* in_sizes, int n_in,
                              void* d_out, int out_size, void* d_ws, size_t ws_size,
                              hipStream_t stream)
{
  const float* x    = (const float*)d_in[0];
  const float* wqkv = (const float*)d_in[1];
  const float* bqkv = (const float*)d_in[2];
  const float* wout = (const float*)d_in[3];
  const float* bout = (const float*)d_in[4];
  float* out = (float*)d_out;

  char* ws = (char*)d_ws;
  unsigned short* xb    = (unsigned short*)(ws);
  unsigned short* wqkvb = (unsigned short*)(ws + ((size_t)16 << 20));
  unsigned short* woutb = (unsigned short*)(ws + ((size_t)24 << 20));
  unsigned short* Qm    = (unsigned short*)(ws + ((size_t)26 << 20));
  unsigned short* Km    = (unsigned short*)(ws + ((size_t)42 << 20));
  unsigned short* VTm   = (unsigned short*)(ws + ((size_t)58 << 20));
  unsigned short* ctx   = (unsigned short*)(ws + ((size_t)74 << 20));
  float* linv = (float*)(ws + ((size_t)90 << 20));

  k_cvt<<<8192, 256, 0, stream>>>(x,    xb);
  k_cvt<<<3072, 256, 0, stream>>>(wqkv, wqkvb);
  k_cvt<<<1024, 256, 0, stream>>>(wout, woutb);

  k_gemm<0><<<1536, 256, 0, stream>>>(xb, wqkvb, bqkv, nullptr, Qm, Km, VTm);
  k_pv     <<<1024, 512, 0, stream>>>(Qm, Km, VTm, linv, ctx);
  k_avg    <<<2048, 256, 0, stream>>>(Qm, Km, linv, out + 8388608);
  k_gemm<1><<< 512, 256, 0, stream>>>(ctx, woutb, bout, out, nullptr, nullptr, nullptr);
}